// Round 7
// baseline (111.068 us; speedup 1.0000x reference)
//
#include <hip/hip_runtime.h>

// PINN beam residual: 1->16->16->2 tanh MLP with analytic 1st/2nd/3rd
// derivatives w.r.t. the scalar input. Outputs (u, w, wx, N, M, Q) concat.
//
// R1: hw tanh (exp2+rcp)        -> 50us, VALU 95%.
// R2: pk over j-pairs (LDS b64) -> 44.6us; pk formed (busy halved) but
//     indexed arrays demoted to scratch (VGPR 56).
// R3/R4: repack attempts        -> same demotion story.
// R5: no arrays, SGPR weights   -> 49.5us == R1: builtin elementwise fma
//     SCALARIZED (no VOP3P broadcast from SGPR operand). VGPR 48.
// R6: inline-asm-pinned v_pk_fma_f32 ("v" constraints -> guaranteed VGPR
//     pairs + guaranteed VOP3P). R2 layout, zero arrays: W2 transposed in
//     LDS (i-rows = 8 contiguous j-pairs, 4x ds_read_b128/i, uniform
//     broadcast), 32 NAMED v2f accumulators, jets splatted once per i
//     (reused by 32 pkfma), scalar epilogue, launch_bounds(256,3).

typedef float v2f __attribute__((ext_vector_type(2)));
typedef float v4f __attribute__((ext_vector_type(4)));

constexpr float EA_CONST = 1000.0f;
constexpr float EI_CONST = 100.0f;
constexpr float TWO_LOG2E = 2.8853900817779268f;

__device__ __forceinline__ v2f pkfma(v2f a, v2f b, v2f c) {
    v2f d;
    asm("v_pk_fma_f32 %0, %1, %2, %3" : "=v"(d) : "v"(a), "v"(b), "v"(c));
    return d;
}

__device__ __forceinline__ float fast_tanh(float x) {
    float e = __builtin_amdgcn_exp2f(x * TWO_LOG2E);
    float r = __builtin_amdgcn_rcpf(1.0f + e);
    return fmaf(-2.0f, r, 1.0f);
}

__global__ __launch_bounds__(256, 3) void pinn_kernel(
    const float* __restrict__ x,
    const float* __restrict__ W1, const float* __restrict__ b1,
    const float* __restrict__ W2, const float* __restrict__ b2,
    const float* __restrict__ W3, const float* __restrict__ b3,
    float* __restrict__ out, int n)
{
    __shared__ float sW2t[256];   // sW2t[i*16 + j] = W2[j*16 + i]
    {
        int t = threadIdx.x;      // t = j*16 + i
        sW2t[(t & 15) * 16 + (t >> 4)] = W2[t];
    }
    __syncthreads();

    int idx = blockIdx.x * blockDim.x + threadIdx.x;
    if (idx >= n) return;
    float xr = x[idx];

    // ---- 32 named v2f accumulators: {z,z',z'',z'''} per j-pair ----
    const v2f* b2v = (const v2f*)b2;
#define DECL(jp)                                                            \
    v2f Z##jp = b2v[jp];                                                    \
    v2f Zp##jp = {0.0f, 0.0f}, Zpp##jp = {0.0f, 0.0f}, Zppp##jp = {0.0f, 0.0f};
    DECL(0) DECL(1) DECL(2) DECL(3) DECL(4) DECL(5) DECL(6) DECL(7)
#undef DECL

    // ---- i-loop: layer-1 jet for unit i, then 32 pinned pkfma ----
#define ACC(jp, wv)                                                         \
    Z##jp    = pkfma(wv, s0, Z##jp);                                        \
    Zp##jp   = pkfma(wv, s1, Zp##jp);                                       \
    Zpp##jp  = pkfma(wv, s2, Zpp##jp);                                      \
    Zppp##jp = pkfma(wv, s3, Zppp##jp);

#define IBODY(i)                                                            \
    {                                                                       \
        float c  = W1[i] * 0.5f;             /* W1_i / L, L = 2 */          \
        float tt = fast_tanh(fmaf(c, xr, b1[i]));                           \
        float t2 = tt * tt;                                                 \
        float p  = 1.0f - t2;                                               \
        float tp = tt * p;                                                  \
        float g  = fmaf(-3.0f, t2, 1.0f);                                   \
        float c2 = c * c;                                                   \
        float a1 = p * c;                                                   \
        float a2 = -2.0f * tp * c2;                                         \
        float a3 = -2.0f * (p * g) * (c2 * c);                              \
        v2f s0 = {tt, tt}, s1 = {a1, a1}, s2 = {a2, a2}, s3 = {a3, a3};     \
        const v4f* rowq = (const v4f*)(sW2t + (i) * 16);                    \
        v4f q0 = rowq[0], q1 = rowq[1], q2 = rowq[2], q3 = rowq[3];         \
        v2f w0 = {q0.x, q0.y}, w1 = {q0.z, q0.w};                           \
        v2f w2 = {q1.x, q1.y}, w3 = {q1.z, q1.w};                           \
        v2f w4 = {q2.x, q2.y}, w5 = {q2.z, q2.w};                           \
        v2f w6 = {q3.x, q3.y}, w7 = {q3.z, q3.w};                           \
        ACC(0, w0) ACC(1, w1) ACC(2, w2) ACC(3, w3)                         \
        ACC(4, w4) ACC(5, w5) ACC(6, w6) ACC(7, w7)                         \
    }
    IBODY(0)  IBODY(1)  IBODY(2)  IBODY(3)
    IBODY(4)  IBODY(5)  IBODY(6)  IBODY(7)
    IBODY(8)  IBODY(9)  IBODY(10) IBODY(11)
    IBODY(12) IBODY(13) IBODY(14) IBODY(15)
#undef IBODY
#undef ACC

    // ---- epilogue per unit j (scalar; W3/b3 uniform -> SGPR) ----
    float u = b3[0], w = b3[1];
    float up = 0.0f, wp = 0.0f, wpp = 0.0f, wppp = 0.0f;
#define EPIJ(zz, zzp, zzpp, zzppp, j)                                       \
    {                                                                       \
        float tt = fast_tanh(zz);                                           \
        float t2 = tt * tt;                                                 \
        float p  = 1.0f - t2;                                               \
        float tp = tt * p;                                                  \
        float g  = fmaf(-3.0f, t2, 1.0f);                                   \
        float zp2 = (zzp) * (zzp);                                          \
        float a2p   = p * (zzp);                                            \
        float a2pp  = fmaf(-2.0f * tp, zp2, p * (zzpp));                    \
        float a2ppp = fmaf(-2.0f * (p * g), zp2 * (zzp),                    \
                           fmaf(-6.0f * tp, (zzp) * (zzpp), p * (zzppp)));  \
        float w30 = W3[j], w31 = W3[16 + (j)];                              \
        u    = fmaf(w30, tt,    u);                                         \
        up   = fmaf(w30, a2p,   up);                                        \
        w    = fmaf(w31, tt,    w);                                         \
        wp   = fmaf(w31, a2p,   wp);                                        \
        wpp  = fmaf(w31, a2pp,  wpp);                                       \
        wppp = fmaf(w31, a2ppp, wppp);                                      \
    }
#define EPIP(jp) \
    EPIJ(Z##jp.x, Zp##jp.x, Zpp##jp.x, Zppp##jp.x, 2 * (jp))                \
    EPIJ(Z##jp.y, Zp##jp.y, Zpp##jp.y, Zppp##jp.y, 2 * (jp) + 1)
    EPIP(0) EPIP(1) EPIP(2) EPIP(3) EPIP(4) EPIP(5) EPIP(6) EPIP(7)
#undef EPIP
#undef EPIJ

    float Nax = EA_CONST * fmaf(0.5f * wp, wp, up);
    out[idx]         = u;
    out[n + idx]     = w;
    out[2 * n + idx] = wp;
    out[3 * n + idx] = Nax;
    out[4 * n + idx] = -EI_CONST * wpp;
    out[5 * n + idx] = fmaf(Nax, wp, -EI_CONST * wppp);
}

extern "C" void kernel_launch(void* const* d_in, const int* in_sizes, int n_in,
                              void* d_out, int out_size, void* d_ws, size_t ws_size,
                              hipStream_t stream) {
    const float* x  = (const float*)d_in[0];
    const float* W1 = (const float*)d_in[1];
    const float* b1 = (const float*)d_in[2];
    const float* W2 = (const float*)d_in[3];
    const float* b2 = (const float*)d_in[4];
    const float* W3 = (const float*)d_in[5];
    const float* b3 = (const float*)d_in[6];
    float* out = (float*)d_out;

    int n = in_sizes[0];
    int block = 256;
    int grid = (n + block - 1) / block;
    pinn_kernel<<<grid, block, 0, stream>>>(x, W1, b1, W2, b2, W3, b3, out, n);
}